// Round 1
// baseline (284.134 us; speedup 1.0000x reference)
//
#include <hip/hip_runtime.h>

typedef unsigned short u16;
typedef unsigned int u32;
typedef __attribute__((ext_vector_type(8))) short bf16x8;   // 8 bf16 = 4 VGPRs
typedef __attribute__((ext_vector_type(4))) float f32x4;

__device__ __forceinline__ u16 f2bf(float f) {
  u32 u = __float_as_uint(f);
  u += 0x7fffu + ((u >> 16) & 1u);   // RNE
  return (u16)(u >> 16);
}

// ---------------- TT merge kernels: build dense W[o][i] (bf16) ----------------
// cores: f0 (1,8,8,16), f1 (16,8,8,16), f2 (16,8,8,16), f3 (16,8,8,1)
// W[o,i] = sum_{r1,r2,r3} f0[0,o0,i0,r1] f1[r1,o1,i1,r2] f2[r2,o2,i2,r3] f3[r3,o3,i3,0]
// o = ((o0*8+o1)*8+o2)*8+o3 , i = ((i0*8+i1)*8+i2)*8+i3

__global__ void merge01(const float* __restrict__ f0, const float* __restrict__ f1,
                        float* __restrict__ W01) {
  int idx = blockIdx.x * 256 + threadIdx.x;      // 65536 = [o0][o1][i0][i1][r2]
  int r2 = idx & 15; int t = idx >> 4;
  int i1 = t & 7; t >>= 3;
  int i0 = t & 7; t >>= 3;
  int o1 = t & 7; int o0 = t >> 3;
  const float* a = f0 + (o0 * 8 + i0) * 16;          // stride over r1 = 1
  const float* b = f1 + (o1 * 8 + i1) * 16 + r2;     // stride over r1 = 1024
  float s = 0.f;
#pragma unroll
  for (int r1 = 0; r1 < 16; ++r1) s += a[r1] * b[r1 * 1024];
  W01[idx] = s;
}

__global__ void merge012(const float* __restrict__ W01, const float* __restrict__ f2,
                         float* __restrict__ W012) {
  int idx = blockIdx.x * 256 + threadIdx.x;      // 4194304 = [o0][o1][o2][i0][i1][i2][r3]
  int r3 = idx & 15; int t = idx >> 4;
  int i2 = t & 7; t >>= 3;
  int i1 = t & 7; t >>= 3;
  int i0 = t & 7; t >>= 3;
  int o2 = t & 7; t >>= 3;
  int o1 = t & 7; int o0 = t >> 3;
  const float* a = W01 + (((o0 * 8 + o1) * 8 + i0) * 8 + i1) * 16;  // stride r2 = 1
  const float* b = f2 + (o2 * 8 + i2) * 16 + r3;                    // stride r2 = 1024
  float s = 0.f;
#pragma unroll
  for (int r2 = 0; r2 < 16; ++r2) s += a[r2] * b[r2 * 1024];
  W012[idx] = s;
}

__global__ void merge_final(const float* __restrict__ W012, const float* __restrict__ f3,
                            u16* __restrict__ W) {
  int idx = blockIdx.x * 256 + threadIdx.x;      // 16777216 = o*4096 + i
  int i = idx & 4095; int o = idx >> 12;
  const float* a = W012 + ((size_t)(o >> 3) * 512 + (i >> 3)) * 16; // stride r3 = 1
  const float* b = f3 + (o & 7) * 8 + (i & 7);                      // stride r3 = 64
  float s = 0.f;
#pragma unroll
  for (int r3 = 0; r3 < 16; ++r3) s += a[r3] * b[r3 * 64];
  W[idx] = f2bf(s);
}

// ---------------- x f32 -> bf16 (vectorized 8/thread) ----------------
__global__ void cvt_x(const float4* __restrict__ x, uint4* __restrict__ xb) {
  int idx = blockIdx.x * 256 + threadIdx.x;      // 2097152 threads * 8 elems
  float4 a = x[idx * 2], b = x[idx * 2 + 1];
  union { u16 h[8]; uint4 v; } r;
  r.h[0] = f2bf(a.x); r.h[1] = f2bf(a.y); r.h[2] = f2bf(a.z); r.h[3] = f2bf(a.w);
  r.h[4] = f2bf(b.x); r.h[5] = f2bf(b.y); r.h[6] = f2bf(b.z); r.h[7] = f2bf(b.w);
  xb[idx] = r.v;
}

// ---------------- bf16 GEMM: C(MxN) = A(MxK) * B(NxK)^T + bias ----------------
// m97 structure: 128x128 tile, BK=32, 4 waves (2x2), 16x16x32 MFMA, width-16
// global_load_lds, 2-barrier K-loop.  LDS read conflict fixed via XOR swizzle
// s = c ^ ((row>>1)&3) applied to the 16B slot index, with the inverse applied
// to the per-lane GLOBAL source address (linear LDS dest, rule #21).
__device__ __forceinline__ void gload_lds16(const void* g, void* l) {
  __builtin_amdgcn_global_load_lds((__attribute__((address_space(1))) void*)(g),
                                   (__attribute__((address_space(3))) void*)(l),
                                   16, 0, 0);
}

__global__ __launch_bounds__(256) void gemm_bt(
    const u16* __restrict__ A, const u16* __restrict__ B,
    const float* __restrict__ bias, float* __restrict__ C) {
  constexpr int K = 4096, N = 4096;
  __shared__ u16 sA[128 * 32];
  __shared__ u16 sB[128 * 32];
  const int tid  = threadIdx.x;
  const int wave = tid >> 6, lane = tid & 63;
  const int bm = (int)(blockIdx.x >> 5) * 128;
  const int bn = (int)(blockIdx.x & 31) * 128;
  const int wr = wave >> 1, wc = wave & 1;

  // staging: each wave fills 2 chunks (16 rows x 32 cols = 1024B) of sA and sB.
  // lane i -> LDS bytes [i*16, i*16+16) = row (i>>2), phys 16B-slot (i&3).
  // phys slot s at row r must hold logical k-chunk s ^ ((r>>1)&3).
  const int ch0 = wave * 2;
  const int qr  = lane >> 2;                        // row within chunk
  const int cl  = (lane & 3) ^ ((qr >> 1) & 3);     // pre-swizzled source chunk
  const size_t rowA0 = (size_t)(bm + ch0 * 16 + qr) * K;
  const size_t rowB0 = (size_t)(bn + ch0 * 16 + qr) * K;
  const int kofs = cl * 8;
  u16* ldsA0 = sA + ch0 * 512;
  u16* ldsB0 = sB + ch0 * 512;

  const int l15 = lane & 15, l4 = lane >> 4;
  const int sw  = (l15 >> 1) & 3;                   // read-side swizzle term

  f32x4 acc[4][4] = {};

  for (int kt = 0; kt < K; kt += 32) {
    __syncthreads();                                 // prev compute done
    gload_lds16(A + rowA0 + kt + kofs,               ldsA0);
    gload_lds16(A + rowA0 + (size_t)16 * K + kt + kofs, ldsA0 + 512);
    gload_lds16(B + rowB0 + kt + kofs,               ldsB0);
    gload_lds16(B + rowB0 + (size_t)16 * K + kt + kofs, ldsB0 + 512);
    __syncthreads();                                 // vmcnt(0) drained by barrier

    bf16x8 af[4], bb[4];
#pragma unroll
    for (int mi = 0; mi < 4; ++mi) {
      int r = wr * 64 + mi * 16 + l15;
      af[mi] = *(const bf16x8*)(sA + r * 32 + ((l4 ^ sw) * 8));
    }
#pragma unroll
    for (int ni = 0; ni < 4; ++ni) {
      int r = wc * 64 + ni * 16 + l15;
      bb[ni] = *(const bf16x8*)(sB + r * 32 + ((l4 ^ sw) * 8));
    }
#pragma unroll
    for (int mi = 0; mi < 4; ++mi)
#pragma unroll
      for (int ni = 0; ni < 4; ++ni)
        acc[mi][ni] = __builtin_amdgcn_mfma_f32_16x16x32_bf16(
            af[mi], bb[ni], acc[mi][ni], 0, 0, 0);
  }

  // epilogue: C row = M-side = (lane>>4)*4 + j, col = N-side = lane&15 (m89-verified)
#pragma unroll
  for (int ni = 0; ni < 4; ++ni) {
    const int col = bn + wc * 64 + ni * 16 + l15;
    const float bv = bias[col];
#pragma unroll
    for (int mi = 0; mi < 4; ++mi) {
      const int row0 = bm + wr * 64 + mi * 16 + l4 * 4;
#pragma unroll
      for (int j = 0; j < 4; ++j)
        C[(size_t)(row0 + j) * N + col] = acc[mi][ni][j] + bv;
    }
  }
}

// ---------------- launch ----------------
// d_in: 0=x (4096x4096 f32), 1=f0, 2=f1, 3=f2, 4=f3, 5=bias (4096 f32)
// d_ws layout (needs 64 MiB total):
//   [0, 32M)        W  bf16 (persists through GEMM)
//   [32M, 64M)      xb bf16 (persists through GEMM)
//     overlaid, used only BEFORE cvt_x runs (same-stream serialization):
//   [32M, 48M)      W012 f32
//   [48M, 48.25M)   W01  f32
extern "C" void kernel_launch(void* const* d_in, const int* in_sizes, int n_in,
                              void* d_out, int out_size, void* d_ws, size_t ws_size,
                              hipStream_t stream) {
  const float* x    = (const float*)d_in[0];
  const float* f0   = (const float*)d_in[1];
  const float* f1   = (const float*)d_in[2];
  const float* f2   = (const float*)d_in[3];
  const float* f3   = (const float*)d_in[4];
  const float* bias = (const float*)d_in[5];

  char* ws = (char*)d_ws;
  u16*   Wb   = (u16*)(ws);
  u16*   xb   = (u16*)(ws + 33554432);
  float* W012 = (float*)(ws + 33554432);           // overlaid with xb (used first)
  float* W01  = (float*)(ws + 33554432 + 16777216);

  merge01   <<<256,   256, 0, stream>>>(f0, f1, W01);
  merge012  <<<16384, 256, 0, stream>>>(W01, f2, W012);
  merge_final<<<65536,256, 0, stream>>>(W012, f3, Wb);
  cvt_x     <<<8192,  256, 0, stream>>>((const float4*)x, (uint4*)xb);
  gemm_bt   <<<1024,  256, 0, stream>>>(xb, Wb, bias, (float*)d_out);
}

// Round 2
// 226.379 us; speedup vs baseline: 1.2551x; 1.2551x over previous
//
#include <hip/hip_runtime.h>

typedef unsigned short u16;
typedef unsigned int u32;
typedef __attribute__((ext_vector_type(8))) short bf16x8;   // 8 bf16 = 4 VGPRs
typedef __attribute__((ext_vector_type(4))) float f32x4;

__device__ __forceinline__ u16 f2bf(float f) {
  u32 u = __float_as_uint(f);
  u += 0x7fffu + ((u >> 16) & 1u);   // RNE
  return (u16)(u >> 16);
}

// ---------------- TT merge kernels: build dense W[o][i] (bf16) ----------------
__global__ void merge01(const float* __restrict__ f0, const float* __restrict__ f1,
                        float* __restrict__ W01) {
  int idx = blockIdx.x * 256 + threadIdx.x;      // 65536 = [o0][o1][i0][i1][r2]
  int r2 = idx & 15; int t = idx >> 4;
  int i1 = t & 7; t >>= 3;
  int i0 = t & 7; t >>= 3;
  int o1 = t & 7; int o0 = t >> 3;
  const float* a = f0 + (o0 * 8 + i0) * 16;
  const float* b = f1 + (o1 * 8 + i1) * 16 + r2;
  float s = 0.f;
#pragma unroll
  for (int r1 = 0; r1 < 16; ++r1) s += a[r1] * b[r1 * 1024];
  W01[idx] = s;
}

__global__ void merge012(const float* __restrict__ W01, const float* __restrict__ f2,
                         float* __restrict__ W012) {
  int idx = blockIdx.x * 256 + threadIdx.x;      // 4194304
  int r3 = idx & 15; int t = idx >> 4;
  int i2 = t & 7; t >>= 3;
  int i1 = t & 7; t >>= 3;
  int i0 = t & 7; t >>= 3;
  int o2 = t & 7; t >>= 3;
  int o1 = t & 7; int o0 = t >> 3;
  const float* a = W01 + (((o0 * 8 + o1) * 8 + i0) * 8 + i1) * 16;
  const float* b = f2 + (o2 * 8 + i2) * 16 + r3;
  float s = 0.f;
#pragma unroll
  for (int r2 = 0; r2 < 16; ++r2) s += a[r2] * b[r2 * 1024];
  W012[idx] = s;
}

__global__ void merge_final(const float* __restrict__ W012, const float* __restrict__ f3,
                            u16* __restrict__ W) {
  int idx = blockIdx.x * 256 + threadIdx.x;      // 16777216 = o*4096 + i
  int i = idx & 4095; int o = idx >> 12;
  const float* a = W012 + ((size_t)(o >> 3) * 512 + (i >> 3)) * 16;
  const float* b = f3 + (o & 7) * 8 + (i & 7);
  float s = 0.f;
#pragma unroll
  for (int r3 = 0; r3 < 16; ++r3) s += a[r3] * b[r3 * 64];
  W[idx] = f2bf(s);
}

// ---------------- x f32 -> bf16 ----------------
__global__ void cvt_x(const float4* __restrict__ x, uint4* __restrict__ xb) {
  int idx = blockIdx.x * 256 + threadIdx.x;
  float4 a = x[idx * 2], b = x[idx * 2 + 1];
  union { u16 h[8]; uint4 v; } r;
  r.h[0] = f2bf(a.x); r.h[1] = f2bf(a.y); r.h[2] = f2bf(a.z); r.h[3] = f2bf(a.w);
  r.h[4] = f2bf(b.x); r.h[5] = f2bf(b.y); r.h[6] = f2bf(b.z); r.h[7] = f2bf(b.w);
  xb[idx] = r.v;
}

// ---------------- 256x256 8-wave pipelined bf16 GEMM  C = A * B^T + bias ------
// 4-slot LDS ring (BK=32, 32 KiB/slot = 128 KiB), counted vmcnt(8), raw
// s_barrier, setprio around MFMA clusters.  Staging tile kt+3 into slot
// (kt+3)&3 only ever overwrites tile kt-1 (consumed) -> race-free.
// LDS swizzle: phys 16B-slot = logical ^ ((row>>1)&3), both sides (rule #21).
__device__ __forceinline__ void gload_lds16(const void* g, void* l) {
  __builtin_amdgcn_global_load_lds((__attribute__((address_space(1))) void*)(g),
                                   (__attribute__((address_space(3))) void*)(l),
                                   16, 0, 0);
}

__global__ __launch_bounds__(512, 2) void gemm256(
    const u16* __restrict__ A, const u16* __restrict__ B,
    const float* __restrict__ bias, float* __restrict__ C) {
  constexpr int K = 4096, N = 4096, NT = 128;
  __shared__ u16 S[65536];                    // [slot4][A 8192 | B 8192]  128 KiB
  const int tid  = threadIdx.x;
  const int wave = tid >> 6, lane = tid & 63;
  const int l15 = lane & 15, l4 = lane >> 4;
  const int wr = wave >> 2, wc = wave & 3;    // 2 x 4 wave grid
  const int bm = (int)(blockIdx.x >> 4) * 256;
  const int bn = (int)(blockIdx.x & 15) * 256;

  // staging precompute: thread covers row rl (of a 128-row half), phys slot tid&3
  const int rl = tid >> 2;
  const int ls = (tid & 3) ^ ((rl >> 1) & 3);          // pre-swizzled source slot
  const u16* srcA0 = A + (size_t)(bm +       rl) * K + ls * 8;
  const u16* srcA1 = A + (size_t)(bm + 128 + rl) * K + ls * 8;
  const u16* srcB0 = B + (size_t)(bn +       rl) * K + ls * 8;
  const u16* srcB1 = B + (size_t)(bn + 128 + rl) * K + ls * 8;
  const int dA0 = wave * 512,         dA1 = 4096  + wave * 512;   // wave-uniform
  const int dB0 = 8192 + wave * 512,  dB1 = 12288 + wave * 512;   // LDS dest (u16)

  // loop-invariant swizzled read offsets (u16 units within a slot)
  int offA[8], offB[4];
#pragma unroll
  for (int mi = 0; mi < 8; ++mi) {
    int r = wr * 128 + mi * 16 + l15;
    offA[mi] = r * 32 + ((l4 ^ ((r >> 1) & 3)) * 8);
  }
#pragma unroll
  for (int ni = 0; ni < 4; ++ni) {
    int r = wc * 64 + ni * 16 + l15;
    offB[ni] = 8192 + r * 32 + ((l4 ^ ((r >> 1) & 3)) * 8);
  }

#define STAGE_A(kts) do { int _s = (kts) & 3; u16* _b = S + _s * 16384;          \
    gload_lds16(srcA0 + (size_t)(kts) * 32, _b + dA0);                           \
    gload_lds16(srcA1 + (size_t)(kts) * 32, _b + dA1); } while (0)
#define STAGE_B(kts) do { int _s = (kts) & 3; u16* _b = S + _s * 16384;          \
    gload_lds16(srcB0 + (size_t)(kts) * 32, _b + dB0);                           \
    gload_lds16(srcB1 + (size_t)(kts) * 32, _b + dB1); } while (0)

  // prologue: stage tiles 0,1,2  (12 loads in flight max)
  STAGE_A(0); STAGE_B(0);
  STAGE_A(1); STAGE_B(1);
  STAGE_A(2); STAGE_B(2);

  f32x4 acc[8][4] = {};

  for (int kt = 0; kt < NT; ++kt) {
    asm volatile("s_waitcnt vmcnt(8)" ::: "memory");   // tile kt landed
    __builtin_amdgcn_s_barrier();
    const u16* base = S + (kt & 3) * 16384;
    const int kn = (kt + 3) & (NT - 1);                // wrap: re-stages garbage, never read

    bf16x8 av[4], bv[4];
    // ---- phase 0: mi 0..3 ----
#pragma unroll
    for (int i = 0; i < 4; ++i) av[i] = *(const bf16x8*)(base + offA[i]);
#pragma unroll
    for (int i = 0; i < 4; ++i) bv[i] = *(const bf16x8*)(base + offB[i]);
    STAGE_A(kn);
    __builtin_amdgcn_s_barrier();
    __builtin_amdgcn_s_setprio(1);
#pragma unroll
    for (int mi = 0; mi < 4; ++mi)
#pragma unroll
      for (int ni = 0; ni < 4; ++ni)
        acc[mi][ni] = __builtin_amdgcn_mfma_f32_16x16x32_bf16(
            av[mi], bv[ni], acc[mi][ni], 0, 0, 0);
    __builtin_amdgcn_s_setprio(0);
    __builtin_amdgcn_s_barrier();

    // ---- phase 1: mi 4..7 (bv reused) ----
#pragma unroll
    for (int i = 0; i < 4; ++i) av[i] = *(const bf16x8*)(base + offA[4 + i]);
    STAGE_B(kn);
    __builtin_amdgcn_s_barrier();
    __builtin_amdgcn_s_setprio(1);
#pragma unroll
    for (int mi = 0; mi < 4; ++mi)
#pragma unroll
      for (int ni = 0; ni < 4; ++ni)
        acc[4 + mi][ni] = __builtin_amdgcn_mfma_f32_16x16x32_bf16(
            av[mi], bv[ni], acc[4 + mi][ni], 0, 0, 0);
    __builtin_amdgcn_s_setprio(0);
    __builtin_amdgcn_s_barrier();
  }

  asm volatile("s_waitcnt vmcnt(0)" ::: "memory");     // drain tail stages

  // epilogue: C row = (lane>>4)*4 + j (M side), col = lane&15 (N side)
#pragma unroll
  for (int ni = 0; ni < 4; ++ni) {
    const int col = bn + wc * 64 + ni * 16 + l15;
    const float bvs = bias[col];
#pragma unroll
    for (int mi = 0; mi < 8; ++mi) {
      const int row0 = bm + wr * 128 + mi * 16 + l4 * 4;
#pragma unroll
      for (int j = 0; j < 4; ++j)
        C[(size_t)(row0 + j) * N + col] = acc[mi][ni][j] + bvs;
    }
  }
#undef STAGE_A
#undef STAGE_B
}

// ---------------- launch ----------------
extern "C" void kernel_launch(void* const* d_in, const int* in_sizes, int n_in,
                              void* d_out, int out_size, void* d_ws, size_t ws_size,
                              hipStream_t stream) {
  const float* x    = (const float*)d_in[0];
  const float* f0   = (const float*)d_in[1];
  const float* f1   = (const float*)d_in[2];
  const float* f2   = (const float*)d_in[3];
  const float* f3   = (const float*)d_in[4];
  const float* bias = (const float*)d_in[5];

  char* ws = (char*)d_ws;
  u16*   Wb   = (u16*)(ws);
  u16*   xb   = (u16*)(ws + 33554432);
  float* W012 = (float*)(ws + 33554432);           // overlaid with xb (used first)
  float* W01  = (float*)(ws + 33554432 + 16777216);

  merge01    <<<256,   256, 0, stream>>>(f0, f1, W01);
  merge012   <<<16384, 256, 0, stream>>>(W01, f2, W012);
  merge_final<<<65536, 256, 0, stream>>>(W012, f3, Wb);
  cvt_x      <<<8192,  256, 0, stream>>>((const float4*)x, (uint4*)xb);
  gemm256    <<<256,   512, 0, stream>>>(xb, Wb, bias, (float*)d_out);
}